// Round 7
// baseline (215.868 us; speedup 1.0000x reference)
//
#include <hip/hip_runtime.h>
#include <cstdint>

#define NN 40000
#define EE 640000
#define DD 128
#define HH 4
#define CC 32
#define LL 2
#define NEG_SLOPE 0.2f
#define NBLK 157   // ceil(NN/256)

typedef __attribute__((ext_vector_type(8))) short bf16x8;
typedef __attribute__((ext_vector_type(8))) unsigned short u16x8;
typedef __attribute__((ext_vector_type(4))) float f32x4;

__device__ __forceinline__ unsigned short f2bf(float f) {
    unsigned u = __float_as_uint(f);
    unsigned r = (u + 0x7FFFu + ((u >> 16) & 1)) >> 16;
    return (unsigned short)r;
}
__device__ __forceinline__ float bf2f(unsigned short u) {
    return __uint_as_float(((unsigned)u) << 16);
}

__device__ __forceinline__ void gload16(const void* g, void* l) {
    __builtin_amdgcn_global_load_lds(
        (const __attribute__((address_space(1))) unsigned*)g,
        (__attribute__((address_space(3))) unsigned*)l, 16, 0, 0);
}

// x fp32 -> bf16 bits
__global__ __launch_bounds__(256) void cvt_kernel(
    const float* __restrict__ in, unsigned short* __restrict__ out)
{
    const int i = blockIdx.x * 256 + threadIdx.x;   // i < NN*DD/4
    if (i >= NN * DD / 4) return;
    const float4 v = ((const float4*)in)[i];
    ushort4 o;
    o.x = f2bf(v.x); o.y = f2bf(v.y); o.z = f2bf(v.z); o.w = f2bf(v.w);
    ((ushort4*)out)[i] = o;
}

// Pack W for both layers into Wb[l][nb(3)][q(16)][n(128)][j(8)] bf16,
// where element = W_nb[l][k = q*8+j][n]   (nb: 0=Wl 1=Wr 2=Wres)
__global__ __launch_bounds__(256) void prepw_kernel(
    const float* __restrict__ Wl, const float* __restrict__ Wr,
    const float* __restrict__ Wres, unsigned short* __restrict__ Wb)
{
    const int i = blockIdx.x * 256 + threadIdx.x;   // i < LL*3*16384
    if (i >= LL * 3 * 16384) return;
    const int l = i / 49152;
    const int rem = i - l * 49152;
    const int nb = rem >> 14;
    const int r2 = rem & 16383;
    const int q = r2 >> 10;
    const int n = (r2 >> 3) & 127;
    const int j = r2 & 7;
    const int k = q * 8 + j;
    const float* W = (nb == 0) ? Wl : (nb == 1) ? Wr : Wres;
    Wb[i] = f2bf(W[(size_t)l * DD * DD + k * DD + n]);
}

// MFMA GEMM: [40000][128] per nb = x_bf16 @ W_nb + b_nb -> xl/xr/res (bf16).
// Block = 128 rows x 128 cols, 4 waves (2x2 of 64x64), K=128 single pass.
// grid (313, 3); last row-block store-guarded (A OOB reads land in next ws buf).
__global__ __launch_bounds__(256) void gemm_mfma_kernel(
    const unsigned short* __restrict__ xb, const unsigned short* __restrict__ Wb,
    const float* __restrict__ bl, const float* __restrict__ br,
    const float* __restrict__ bias,
    unsigned short* __restrict__ xlb, unsigned short* __restrict__ xrb,
    unsigned short* __restrict__ resb)
{
    __shared__ __align__(16) unsigned short lds[32768];  // A:0..16383, B:16384..32767
    const int lane = threadIdx.x & 63;
    const int wv = threadIdx.x >> 6;
    const int row0 = blockIdx.x << 7;
    const int nb = blockIdx.y;

    const unsigned short* WbN = Wb + (size_t)nb * 16384;
    // A layout: [q][g][lane][8] (g = row-half); B layout: [q][n][8]
#pragma unroll
    for (int jj = 0; jj < 4; ++jj) {
        const int q = jj * 4 + wv;
        gload16(xb + (size_t)(row0 + lane) * DD + q * 8,      &lds[(q * 2 + 0) * 512]);
        gload16(xb + (size_t)(row0 + 64 + lane) * DD + q * 8, &lds[(q * 2 + 1) * 512]);
        gload16(WbN + q * 1024 + lane * 8,                    &lds[16384 + q * 1024]);
        gload16(WbN + q * 1024 + 512 + lane * 8,              &lds[16384 + q * 1024 + 512]);
    }
    __syncthreads();

    const int wm = wv >> 1, wn = wv & 1;
    const int h = lane >> 4, r = lane & 15;
    f32x4 acc[4][4] = {};
#pragma unroll
    for (int s = 0; s < 4; ++s) {
        const int q = s * 4 + h;
        bf16x8 a[4], b[4];
#pragma unroll
        for (int mi = 0; mi < 4; ++mi)
            a[mi] = *(const bf16x8*)&lds[(q * 2 + wm) * 512 + (mi * 16 + r) * 8];
#pragma unroll
        for (int ni = 0; ni < 4; ++ni)
            b[ni] = *(const bf16x8*)&lds[16384 + q * 1024 + (wn * 64 + ni * 16 + r) * 8];
#pragma unroll
        for (int mi = 0; mi < 4; ++mi)
#pragma unroll
            for (int ni = 0; ni < 4; ++ni)
                acc[mi][ni] = __builtin_amdgcn_mfma_f32_16x16x32_bf16(
                    a[mi], b[ni], acc[mi][ni], 0, 0, 0);
    }

    unsigned short* const outp = (nb == 0) ? xlb : (nb == 1) ? xrb : resb;
    const float* const bp = (nb == 0) ? bl : (nb == 1) ? br : bias;
#pragma unroll
    for (int ni = 0; ni < 4; ++ni) {
        const int col = wn * 64 + ni * 16 + r;
        const float bv = bp[col];
#pragma unroll
        for (int mi = 0; mi < 4; ++mi) {
            const int rw = row0 + wm * 64 + mi * 16 + h * 4;
#pragma unroll
            for (int v = 0; v < 4; ++v) {
                const int rr = rw + v;
                if (rr < NN)
                    outp[(size_t)rr * DD + col] = f2bf(acc[mi][ni][v] + bv);
            }
        }
    }
}

// ---------------- CSR build (once per call; dst is layer-invariant) --------

__global__ __launch_bounds__(256) void zero_deg_kernel(int* __restrict__ deg)
{
    const int i = blockIdx.x * 256 + threadIdx.x;
    if (i < NN) deg[i] = 0;
}

__global__ __launch_bounds__(256) void hist_kernel(
    const int* __restrict__ dst, int* __restrict__ deg)
{
    const int e = blockIdx.x * 256 + threadIdx.x;
    if (e < EE) atomicAdd(&deg[dst[e]], 1);
}

__global__ __launch_bounds__(256) void scan1_kernel(
    const int* __restrict__ deg, int* __restrict__ rowptr, int* __restrict__ blksum)
{
    __shared__ int s[256];
    const int i = blockIdx.x * 256 + threadIdx.x;
    const int v = (i < NN) ? deg[i] : 0;
    s[threadIdx.x] = v;
    __syncthreads();
    for (int off = 1; off < 256; off <<= 1) {
        const int t = (threadIdx.x >= off) ? s[threadIdx.x - off] : 0;
        __syncthreads();
        s[threadIdx.x] += t;
        __syncthreads();
    }
    if (i < NN) rowptr[i] = s[threadIdx.x] - v;
    if (threadIdx.x == 255) blksum[blockIdx.x] = s[255];
}

__global__ __launch_bounds__(256) void scan2_kernel(int* __restrict__ blksum)
{
    __shared__ int s[256];
    const int v = (threadIdx.x < NBLK) ? blksum[threadIdx.x] : 0;
    s[threadIdx.x] = v;
    __syncthreads();
    for (int off = 1; off < 256; off <<= 1) {
        const int t = (threadIdx.x >= off) ? s[threadIdx.x - off] : 0;
        __syncthreads();
        s[threadIdx.x] += t;
        __syncthreads();
    }
    if (threadIdx.x < NBLK) blksum[threadIdx.x] = s[threadIdx.x] - v;
}

__global__ __launch_bounds__(256) void scan3_kernel(
    int* __restrict__ rowptr, const int* __restrict__ blksum, int* __restrict__ cursor)
{
    const int i = blockIdx.x * 256 + threadIdx.x;
    if (i < NN) {
        const int v = rowptr[i] + blksum[blockIdx.x];
        rowptr[i] = v;
        cursor[i] = v;
    }
    if (i == 0) rowptr[NN] = EE;
}

// colb[p] = src * 256  (byte offset of the source row in xlb)
__global__ __launch_bounds__(256) void fill_kernel(
    const int* __restrict__ src, const int* __restrict__ dst,
    int* __restrict__ cursor, int* __restrict__ colb)
{
    const int e = blockIdx.x * 256 + threadIdx.x;
    if (e < EE) {
        const int p = atomicAdd(&cursor[dst[e]], 1);
        colb[p] = src[e] << 8;
    }
}

// ------------- fused score + softmax (no-max, fp32-safe) + agg + ELU -------
// one wave per dst node; lane owns 8 channels (hl = lane&15, head = hl>>2);
// 4 lane-groups (g = lane>>4) process disjoint edges; 8 edges per chunk
__global__ __launch_bounds__(256) void gather_kernel(
    const unsigned short* __restrict__ xlb, const unsigned short* __restrict__ xrb,
    const unsigned short* __restrict__ resb,
    const int* __restrict__ rowptr, const int* __restrict__ colb,
    const float* __restrict__ att,
    float* __restrict__ outf, unsigned short* __restrict__ outb)
{
    const int node = (blockIdx.x * 256 + threadIdx.x) >> 6;
    const int lane = threadIdx.x & 63;
    if (node >= NN) return;
    const int g  = lane >> 4;
    const int hl = lane & 15;          // channels [hl*8, hl*8+8)

    const u16x8 xu = *(const u16x8*)(xrb + (size_t)node * DD + hl * 8);
    float xr[8], at[8];
#pragma unroll
    for (int c = 0; c < 8; ++c) xr[c] = bf2f(xu[c]);
    const float4 at0 = ((const float4*)(att + hl * 8))[0];
    const float4 at1 = ((const float4*)(att + hl * 8))[1];
    at[0]=at0.x; at[1]=at0.y; at[2]=at0.z; at[3]=at0.w;
    at[4]=at1.x; at[5]=at1.y; at[6]=at1.z; at[7]=at1.w;

    float d = 0.f, acc[8] = {0,0,0,0,0,0,0,0};
    const int beg = rowptr[node], end = rowptr[node + 1];
    const char* const xbase = (const char*)xlb;

    int p = beg;
    for (; p + 8 <= end; p += 8) {     // unmasked main loop
#pragma unroll
        for (int j = 0; j < 2; ++j) {
            const int off = colb[p + j * 4 + g];
            const u16x8 u = *(const u16x8*)(xbase + off + hl * 16);
            float xv[8], al = 0.f;
#pragma unroll
            for (int c = 0; c < 8; ++c) {
                xv[c] = bf2f(u[c]);
                float z = xv[c] + xr[c];
                z = fmaxf(z, NEG_SLOPE * z);
                al = fmaf(z, at[c], al);
            }
            al += __shfl_xor(al, 1);
            al += __shfl_xor(al, 2);   // per-head score (4 lanes/head)
            const float w = __expf(al);
            d += w;
#pragma unroll
            for (int c = 0; c < 8; ++c) acc[c] = fmaf(w, xv[c], acc[c]);
        }
    }
    if (p < end) {                     // masked tail (1..7 edges)
#pragma unroll
        for (int j = 0; j < 2; ++j) {
            const int q = p + j * 4 + g;
            const bool ok = (q < end);
            const int off = colb[ok ? q : beg];
            const u16x8 u = *(const u16x8*)(xbase + off + hl * 16);
            float xv[8], al = 0.f;
#pragma unroll
            for (int c = 0; c < 8; ++c) {
                xv[c] = bf2f(u[c]);
                float z = xv[c] + xr[c];
                z = fmaxf(z, NEG_SLOPE * z);
                al = fmaf(z, at[c], al);
            }
            al += __shfl_xor(al, 1);
            al += __shfl_xor(al, 2);
            const float w = ok ? __expf(al) : 0.f;
            d += w;
#pragma unroll
            for (int c = 0; c < 8; ++c) acc[c] = fmaf(w, xv[c], acc[c]);
        }
    }

    // combine the 4 edge-groups (disjoint edges, same channels)
    d += __shfl_xor(d, 16);
    d += __shfl_xor(d, 32);
#pragma unroll
    for (int c = 0; c < 8; ++c) {
        acc[c] += __shfl_xor(acc[c], 16);
        acc[c] += __shfl_xor(acc[c], 32);
    }

    if (g == 0) {
        const float inv = 1.f / (d + 1e-16f);
        const u16x8 ru = *(const u16x8*)(resb + (size_t)node * DD + hl * 8);
        float o[8];
#pragma unroll
        for (int c = 0; c < 8; ++c) {
            float v = acc[c] * inv + bf2f(ru[c]);
            o[c] = (v > 0.f) ? v : expm1f(v);
        }
        if (outf) {
            float4 f0, f1;
            f0.x=o[0]; f0.y=o[1]; f0.z=o[2]; f0.w=o[3];
            f1.x=o[4]; f1.y=o[5]; f1.z=o[6]; f1.w=o[7];
            ((float4*)(outf + (size_t)node * DD + hl * 8))[0] = f0;
            ((float4*)(outf + (size_t)node * DD + hl * 8))[1] = f1;
        }
        if (outb) {
            u16x8 ob;
#pragma unroll
            for (int c = 0; c < 8; ++c) ob[c] = f2bf(o[c]);
            *(u16x8*)(outb + (size_t)node * DD + hl * 8) = ob;
        }
    }
}

extern "C" void kernel_launch(void* const* d_in, const int* in_sizes, int n_in,
                              void* d_out, int out_size, void* d_ws, size_t ws_size,
                              hipStream_t stream)
{
    const float* x0   = (const float*)d_in[0];
    const int*   ei   = (const int*)  d_in[1];
    const float* Wl   = (const float*)d_in[2];
    const float* bl   = (const float*)d_in[3];
    const float* Wr   = (const float*)d_in[4];
    const float* br   = (const float*)d_in[5];
    const float* att  = (const float*)d_in[6];
    const float* Wres = (const float*)d_in[7];
    const float* bias = (const float*)d_in[8];
    const int* src = ei;
    const int* dst = ei + EE;

    float* p = (float*)d_ws;
    unsigned short* xlb  = (unsigned short*)p; p += (size_t)NN * DD / 2;
    unsigned short* xrb  = (unsigned short*)p; p += (size_t)NN * DD / 2;
    unsigned short* resb = (unsigned short*)p; p += (size_t)NN * DD / 2;
    unsigned short* xb0  = (unsigned short*)p; p += (size_t)NN * DD / 2;
    unsigned short* xb1  = (unsigned short*)p; p += (size_t)NN * DD / 2;
    unsigned short* Wb   = (unsigned short*)p; p += LL * 3 * 16384 / 2;
    int* rowptr = (int*)p; p += NN + 1;
    int* deg    = (int*)p; p += NN;
    int* cursor = (int*)p; p += NN;
    int* blksum = (int*)p; p += NBLK;
    int* colb   = (int*)p; p += EE;

    // CSR build (dst fixed across layers)
    zero_deg_kernel<<<NBLK, 256, 0, stream>>>(deg);
    hist_kernel<<<(EE + 255) / 256, 256, 0, stream>>>(dst, deg);
    scan1_kernel<<<NBLK, 256, 0, stream>>>(deg, rowptr, blksum);
    scan2_kernel<<<1, 256, 0, stream>>>(blksum);
    scan3_kernel<<<NBLK, 256, 0, stream>>>(rowptr, blksum, cursor);
    fill_kernel<<<(EE + 255) / 256, 256, 0, stream>>>(src, dst, cursor, colb);

    cvt_kernel<<<(NN * DD / 4 + 255) / 256, 256, 0, stream>>>(x0, xb0);
    prepw_kernel<<<(LL * 3 * 16384 + 255) / 256, 256, 0, stream>>>(Wl, Wr, Wres, Wb);

    for (int l = 0; l < LL; ++l) {
        const unsigned short* xin = (l == 0) ? xb0 : xb1;
        gemm_mfma_kernel<<<dim3(313, 3), 256, 0, stream>>>(
            xin, Wb + (size_t)l * 3 * 16384, bl + l * DD, br + l * DD, bias + l * DD,
            xlb, xrb, resb);
        gather_kernel<<<(NN * 64 + 255) / 256, 256, 0, stream>>>(
            xlb, xrb, resb, rowptr, colb, att + (size_t)l * HH * CC,
            (l == LL - 1) ? (float*)d_out : nullptr,
            (l == 0) ? xb1 : nullptr);
    }
}

// Round 8
// 170.353 us; speedup vs baseline: 1.2672x; 1.2672x over previous
//
#include <hip/hip_runtime.h>
#include <cstdint>

#define NN 40000
#define EE 640000
#define DD 128
#define HH 4
#define CC 32
#define LL 2
#define NEG_SLOPE 0.2f
#define NBLK 157   // ceil(NN/256)

typedef __attribute__((ext_vector_type(8))) short bf16x8;
typedef __attribute__((ext_vector_type(4))) float f32x4;

__device__ __forceinline__ unsigned short f2bf(float f) {
    unsigned u = __float_as_uint(f);
    unsigned r = (u + 0x7FFFu + ((u >> 16) & 1)) >> 16;
    return (unsigned short)r;
}
__device__ __forceinline__ float bf2f(unsigned short u) {
    return __uint_as_float(((unsigned)u) << 16);
}

__device__ __forceinline__ void gload16(const void* g, void* l) {
    __builtin_amdgcn_global_load_lds(
        (const __attribute__((address_space(1))) unsigned*)g,
        (__attribute__((address_space(3))) unsigned*)l, 16, 0, 0);
}

// Fused prep: x fp32->bf16 ; W pack (both layers) ; deg zero.
// Wb[l*49152 + nb*8192 + q*512 + n*8 + j] = W_sel[l][k=q*8+j][(nb&1)*64+n]
__global__ __launch_bounds__(256) void prep_kernel(
    const float* __restrict__ x,
    const float* __restrict__ Wl, const float* __restrict__ Wr,
    const float* __restrict__ Wres,
    unsigned short* __restrict__ xb, unsigned short* __restrict__ Wb,
    int* __restrict__ deg)
{
    const int i = blockIdx.x * 256 + threadIdx.x;
    if (i < NN * DD / 4) {
        const float4 v = ((const float4*)x)[i];
        ushort4 o;
        o.x = f2bf(v.x); o.y = f2bf(v.y); o.z = f2bf(v.z); o.w = f2bf(v.w);
        ((ushort4*)xb)[i] = o;
    }
    if (i < LL * 6 * 8192) {
        const int l = i / 49152;
        const int rem0 = i - l * 49152;
        const int nb = rem0 >> 13;
        const int rem = rem0 & 8191;
        const int q = rem >> 9;
        const int n = (rem >> 3) & 63;
        const int j = rem & 7;
        const int k = q * 8 + j;
        const int colg = (nb & 1) * 64 + n;
        const float* W = (nb < 2) ? Wl : (nb < 4) ? Wr : Wres;
        Wb[i] = f2bf(W[(size_t)l * DD * DD + k * DD + colg]);
    }
    if (i < NN) deg[i] = 0;
}

// MFMA GEMM: [40000][384] = x_bf16 @ [Wl|Wr|Wres] + bias -> xl/xr/res (bf16).
// Block = 64 rows; A staged once; loop t over 6 (matrix, col-half) B-tiles.
// 4 waves, each 32x32 of the 64x64 per-t tile. grid(625). 40000 = 625*64 exact.
__global__ __launch_bounds__(256) void gemm_mfma_kernel(
    const unsigned short* __restrict__ xb, const unsigned short* __restrict__ Wb,
    const float* __restrict__ bl, const float* __restrict__ br,
    const float* __restrict__ bias,
    unsigned short* __restrict__ xlb, unsigned short* __restrict__ xrb,
    unsigned short* __restrict__ resb)
{
    __shared__ __align__(16) unsigned short lds[16384];  // A:0..8191, B:8192..16383
    const int lane = threadIdx.x & 63;
    const int wv = threadIdx.x >> 6;
    const int row0 = blockIdx.x << 6;

    // stage A once: layout [q(16)][row(64)][8]
#pragma unroll
    for (int j = 0; j < 4; ++j) {
        const int q = j * 4 + wv;
        gload16(xb + (size_t)(row0 + lane) * DD + q * 8, &lds[q * 512]);
    }

    const int wm = wv >> 1, wn = wv & 1;
    const int h = lane >> 4, r = lane & 15;

    for (int t = 0; t < 6; ++t) {
        __syncthreads();   // prior readers of B done (and A-loads drained on t=0)
#pragma unroll
        for (int j = 0; j < 4; ++j) {
            const int q = j * 4 + wv;
            gload16(Wb + (size_t)t * 8192 + q * 512 + lane * 8, &lds[8192 + q * 512]);
        }
        __syncthreads();   // A + B_t resident

        f32x4 acc[2][2] = {{{0.f,0.f,0.f,0.f},{0.f,0.f,0.f,0.f}},
                           {{0.f,0.f,0.f,0.f},{0.f,0.f,0.f,0.f}}};
#pragma unroll
        for (int s = 0; s < 4; ++s) {
            const int base = (s * 4 + h) * 64;
            const bf16x8 a0 = *(const bf16x8*)&lds[(base + wm * 32 + r) * 8];
            const bf16x8 a1 = *(const bf16x8*)&lds[(base + wm * 32 + 16 + r) * 8];
            const bf16x8 b0 = *(const bf16x8*)&lds[8192 + (base + wn * 32 + r) * 8];
            const bf16x8 b1 = *(const bf16x8*)&lds[8192 + (base + wn * 32 + 16 + r) * 8];
            acc[0][0] = __builtin_amdgcn_mfma_f32_16x16x32_bf16(a0, b0, acc[0][0], 0, 0, 0);
            acc[0][1] = __builtin_amdgcn_mfma_f32_16x16x32_bf16(a0, b1, acc[0][1], 0, 0, 0);
            acc[1][0] = __builtin_amdgcn_mfma_f32_16x16x32_bf16(a1, b0, acc[1][0], 0, 0, 0);
            acc[1][1] = __builtin_amdgcn_mfma_f32_16x16x32_bf16(a1, b1, acc[1][1], 0, 0, 0);
        }

        unsigned short* const outp = (t < 2) ? xlb : (t < 4) ? xrb : resb;
        const float* const bp = (t < 2) ? bl : (t < 4) ? br : bias;
        const int c0 = (t & 1) * 64 + wn * 32;
#pragma unroll
        for (int ni = 0; ni < 2; ++ni) {
            const int col = c0 + ni * 16 + r;
            const float bv = bp[col];
#pragma unroll
            for (int mi = 0; mi < 2; ++mi) {
                const int rw = row0 + wm * 32 + mi * 16 + h * 4;
#pragma unroll
                for (int v = 0; v < 4; ++v)
                    outp[(size_t)(rw + v) * DD + col] = f2bf(acc[mi][ni][v] + bv);
            }
        }
    }
}

// ---------------- CSR build (once per call; dst is layer-invariant) --------

__global__ __launch_bounds__(256) void hist_kernel(
    const int* __restrict__ dst, int* __restrict__ deg)
{
    const int e = blockIdx.x * 256 + threadIdx.x;
    if (e < EE) atomicAdd(&deg[dst[e]], 1);
}

__global__ __launch_bounds__(256) void scan1_kernel(
    const int* __restrict__ deg, int* __restrict__ rowptr, int* __restrict__ blksum)
{
    __shared__ int s[256];
    const int i = blockIdx.x * 256 + threadIdx.x;
    const int v = (i < NN) ? deg[i] : 0;
    s[threadIdx.x] = v;
    __syncthreads();
    for (int off = 1; off < 256; off <<= 1) {
        const int t = (threadIdx.x >= off) ? s[threadIdx.x - off] : 0;
        __syncthreads();
        s[threadIdx.x] += t;
        __syncthreads();
    }
    if (i < NN) rowptr[i] = s[threadIdx.x] - v;
    if (threadIdx.x == 255) blksum[blockIdx.x] = s[255];
}

__global__ __launch_bounds__(256) void scan2_kernel(int* __restrict__ blksum)
{
    __shared__ int s[256];
    const int v = (threadIdx.x < NBLK) ? blksum[threadIdx.x] : 0;
    s[threadIdx.x] = v;
    __syncthreads();
    for (int off = 1; off < 256; off <<= 1) {
        const int t = (threadIdx.x >= off) ? s[threadIdx.x - off] : 0;
        __syncthreads();
        s[threadIdx.x] += t;
        __syncthreads();
    }
    if (threadIdx.x < NBLK) blksum[threadIdx.x] = s[threadIdx.x] - v;
}

__global__ __launch_bounds__(256) void scan3_kernel(
    int* __restrict__ rowptr, const int* __restrict__ blksum, int* __restrict__ cursor)
{
    const int i = blockIdx.x * 256 + threadIdx.x;
    if (i < NN) {
        const int v = rowptr[i] + blksum[blockIdx.x];
        rowptr[i] = v;
        cursor[i] = v;
    }
    if (i == 0) rowptr[NN] = EE;
}

// colb[p] = src * 256  (byte offset of the source row in xlb)
__global__ __launch_bounds__(256) void fill_kernel(
    const int* __restrict__ src, const int* __restrict__ dst,
    int* __restrict__ cursor, int* __restrict__ colb)
{
    const int e = blockIdx.x * 256 + threadIdx.x;
    if (e < EE) {
        const int p = atomicAdd(&cursor[dst[e]], 1);
        colb[p] = src[e] << 8;
    }
}

// ------------- fused score + softmax (no-max, fp32-safe) + agg + ELU -------
// one wave per dst node; lane owns 4 channels (hl = lane&31);
// wave-halves process disjoint edges; 8 edges (2x4 slots) per chunk;
// unmasked main loop + masked tail
__global__ __launch_bounds__(256) void gather_kernel(
    const unsigned short* __restrict__ xlb, const unsigned short* __restrict__ xrb,
    const unsigned short* __restrict__ resb,
    const int* __restrict__ rowptr, const int* __restrict__ colb,
    const float* __restrict__ att,
    float* __restrict__ outf, unsigned short* __restrict__ outb)
{
    const int node = (blockIdx.x * 256 + threadIdx.x) >> 6;
    const int lane = threadIdx.x & 63;
    if (node >= NN) return;
    const int halfid = lane >> 5;
    const int hl = lane & 31;          // owns channels [hl*4, hl*4+4)

    const ushort4 xru = ((const ushort4*)(xrb + (size_t)node * DD))[hl];
    const float xr0 = bf2f(xru.x), xr1 = bf2f(xru.y);
    const float xr2 = bf2f(xru.z), xr3 = bf2f(xru.w);
    const float4 attv = ((const float4*)att)[hl];
    const char* const xbase = (const char*)xlb;

    float d = 0.f, a0 = 0.f, a1 = 0.f, a2 = 0.f, a3 = 0.f;
    const int beg = rowptr[node], end = rowptr[node + 1];

    int p = beg;
    for (; p + 8 <= end; p += 8) {     // unmasked main loop
        float xv[4][4], al[4];
#pragma unroll
        for (int i = 0; i < 4; ++i) {
            const int off = colb[p + 2 * i + halfid];
            const ushort4 u = *(const ushort4*)(xbase + off + hl * 8);
            xv[i][0] = bf2f(u.x); xv[i][1] = bf2f(u.y);
            xv[i][2] = bf2f(u.z); xv[i][3] = bf2f(u.w);
        }
#pragma unroll
        for (int i = 0; i < 4; ++i) {
            float z0 = xv[i][0] + xr0; z0 = fmaxf(z0, NEG_SLOPE * z0);
            float z1 = xv[i][1] + xr1; z1 = fmaxf(z1, NEG_SLOPE * z1);
            float z2 = xv[i][2] + xr2; z2 = fmaxf(z2, NEG_SLOPE * z2);
            float z3 = xv[i][3] + xr3; z3 = fmaxf(z3, NEG_SLOPE * z3);
            al[i] = z0 * attv.x + z1 * attv.y + z2 * attv.z + z3 * attv.w;
        }
#pragma unroll
        for (int o = 1; o <= 4; o <<= 1) {
#pragma unroll
            for (int i = 0; i < 4; ++i) al[i] += __shfl_xor(al[i], o);
        }
#pragma unroll
        for (int i = 0; i < 4; ++i) {
            const float w = __expf(al[i]);
            d  += w;
            a0 += w * xv[i][0]; a1 += w * xv[i][1];
            a2 += w * xv[i][2]; a3 += w * xv[i][3];
        }
    }
    if (p < end) {                     // masked tail (1..7 edges)
        float xv[4][4], al[4];
        int vl[4];
#pragma unroll
        for (int i = 0; i < 4; ++i) {
            const int q = p + 2 * i + halfid;
            vl[i] = (q < end);
            const int off = colb[vl[i] ? q : beg];
            const ushort4 u = *(const ushort4*)(xbase + off + hl * 8);
            xv[i][0] = bf2f(u.x); xv[i][1] = bf2f(u.y);
            xv[i][2] = bf2f(u.z); xv[i][3] = bf2f(u.w);
        }
#pragma unroll
        for (int i = 0; i < 4; ++i) {
            float z0 = xv[i][0] + xr0; z0 = fmaxf(z0, NEG_SLOPE * z0);
            float z1 = xv[i][1] + xr1; z1 = fmaxf(z1, NEG_SLOPE * z1);
            float z2 = xv[i][2] + xr2; z2 = fmaxf(z2, NEG_SLOPE * z2);
            float z3 = xv[i][3] + xr3; z3 = fmaxf(z3, NEG_SLOPE * z3);
            al[i] = z0 * attv.x + z1 * attv.y + z2 * attv.z + z3 * attv.w;
        }
#pragma unroll
        for (int o = 1; o <= 4; o <<= 1) {
#pragma unroll
            for (int i = 0; i < 4; ++i) al[i] += __shfl_xor(al[i], o);
        }
#pragma unroll
        for (int i = 0; i < 4; ++i) {
            const float w = vl[i] ? __expf(al[i]) : 0.f;
            d  += w;
            a0 += w * xv[i][0]; a1 += w * xv[i][1];
            a2 += w * xv[i][2]; a3 += w * xv[i][3];
        }
    }

    // combine the two halves (disjoint edge subsets, same channels)
    d  += __shfl_xor(d, 32);
    a0 += __shfl_xor(a0, 32); a1 += __shfl_xor(a1, 32);
    a2 += __shfl_xor(a2, 32); a3 += __shfl_xor(a3, 32);

    if (halfid == 0) {
        const float inv = 1.f / (d + 1e-16f);
        const ushort4 ru = ((const ushort4*)(resb + (size_t)node * DD))[hl];
        float o0 = a0 * inv + bf2f(ru.x);
        float o1 = a1 * inv + bf2f(ru.y);
        float o2 = a2 * inv + bf2f(ru.z);
        float o3 = a3 * inv + bf2f(ru.w);
        o0 = (o0 > 0.f) ? o0 : expm1f(o0);
        o1 = (o1 > 0.f) ? o1 : expm1f(o1);
        o2 = (o2 > 0.f) ? o2 : expm1f(o2);
        o3 = (o3 > 0.f) ? o3 : expm1f(o3);
        if (outf) {
            float4 ov; ov.x = o0; ov.y = o1; ov.z = o2; ov.w = o3;
            ((float4*)(outf + (size_t)node * DD))[hl] = ov;
        }
        if (outb) {
            ushort4 ob;
            ob.x = f2bf(o0); ob.y = f2bf(o1); ob.z = f2bf(o2); ob.w = f2bf(o3);
            ((ushort4*)(outb + (size_t)node * DD))[hl] = ob;
        }
    }
}

extern "C" void kernel_launch(void* const* d_in, const int* in_sizes, int n_in,
                              void* d_out, int out_size, void* d_ws, size_t ws_size,
                              hipStream_t stream)
{
    const float* x0   = (const float*)d_in[0];
    const int*   ei   = (const int*)  d_in[1];
    const float* Wl   = (const float*)d_in[2];
    const float* bl   = (const float*)d_in[3];
    const float* Wr   = (const float*)d_in[4];
    const float* br   = (const float*)d_in[5];
    const float* att  = (const float*)d_in[6];
    const float* Wres = (const float*)d_in[7];
    const float* bias = (const float*)d_in[8];
    const int* src = ei;
    const int* dst = ei + EE;

    float* p = (float*)d_ws;
    unsigned short* xlb  = (unsigned short*)p; p += (size_t)NN * DD / 2;
    unsigned short* xrb  = (unsigned short*)p; p += (size_t)NN * DD / 2;
    unsigned short* resb = (unsigned short*)p; p += (size_t)NN * DD / 2;
    unsigned short* xb0  = (unsigned short*)p; p += (size_t)NN * DD / 2;
    unsigned short* xb1  = (unsigned short*)p; p += (size_t)NN * DD / 2;
    unsigned short* Wb   = (unsigned short*)p; p += LL * 6 * 8192 / 2;
    int* rowptr = (int*)p; p += NN + 1;
    int* deg    = (int*)p; p += NN;
    int* cursor = (int*)p; p += NN;
    int* blksum = (int*)p; p += NBLK;
    int* colb   = (int*)p; p += EE;

    // prep (cvt + W pack + deg zero), then CSR build (dst fixed across layers)
    prep_kernel<<<(NN * DD / 4 + 255) / 256, 256, 0, stream>>>(
        x0, Wl, Wr, Wres, xb0, Wb, deg);
    hist_kernel<<<(EE + 255) / 256, 256, 0, stream>>>(dst, deg);
    scan1_kernel<<<NBLK, 256, 0, stream>>>(deg, rowptr, blksum);
    scan2_kernel<<<1, 256, 0, stream>>>(blksum);
    scan3_kernel<<<NBLK, 256, 0, stream>>>(rowptr, blksum, cursor);
    fill_kernel<<<(EE + 255) / 256, 256, 0, stream>>>(src, dst, cursor, colb);

    for (int l = 0; l < LL; ++l) {
        const unsigned short* xin = (l == 0) ? xb0 : xb1;
        gemm_mfma_kernel<<<625, 256, 0, stream>>>(
            xin, Wb + (size_t)l * 6 * 8192, bl + l * DD, br + l * DD, bias + l * DD,
            xlb, xrb, resb);
        gather_kernel<<<(NN * 64 + 255) / 256, 256, 0, stream>>>(
            xlb, xrb, resb, rowptr, colb, att + (size_t)l * HH * CC,
            (l == LL - 1) ? (float*)d_out : nullptr,
            (l == 0) ? xb1 : nullptr);
    }
}